// Round 9
// baseline (40940.231 us; speedup 1.0000x reference)
//
#include <hip/hip_runtime.h>
#include <math.h>

// Backprop_29188597744223 — 1024-step sequential MLP training scan.
//
//   k_gram : G = X·Xᵀ, grid-parallel
//   k_z10  : Z10 = X·W1_init, grid-parallel
//   k2_seq : ONE workgroup, 256 threads (4 waves). VGPR budget rule
//            (measured R2-R8): 65536/threads -> 256 regs. Thread (p,q),
//            p=tid>>5 (8 groups), q=tid&31. W2 rows 0..135 in registers
//            (17 f32x8/thread), rows 136..255 in LDS split-half layout
//            W2LA/W2LB (q*4 dword stride = conflict-free b128). W3 in regs
//            (64 scalars/thread). 32-step blocks; o1 history bf16 in LDS;
//            z1p in global with per-step LDS ping-pong prefetch.
//   k_w1out: W1_final = s1_f·(W1_init + Xᵀ·diag(c)·O1), grid-parallel

#define LRC  0.01f
#define EPSV 1e-8f

typedef float f32x8 __attribute__((ext_vector_type(8)));
typedef unsigned int uint32;
typedef unsigned short ushort;

// ---- LDS layout (float offsets) ----
#define W2LA_OFF  0        // [120][128]
#define W2LB_OFF  15360    // [120][128]
#define O1STG_OFF 30720    // 4224: prefix o1 staging [16][264] f32 / o1h [32][264] bf16
#define SCRB_OFF  34944    // [8][264]
#define SCR3_OFF  37056    // [64][9] / prefix G [16][17]
#define Z1PRE_OFF 37632    // [2][256]
#define GPRE_OFF  38144    // [2][32]
#define TPRE_OFF  38208    // [2][64]
#define A1V_OFF   38336
#define Z1V_OFF   38592
#define Z2V_OFF   38848
#define A2V_OFF   39104
#define O2V_OFF   39360
#define O1V_OFF   39616
#define B1V_OFF   39872
#define B2V_OFF   40128
#define Z3V_OFF   40384
#define D3V_OFF   40448
#define B3V_OFF   40512
#define CH_OFF    40576
#define DTS_OFF   40608
#define CPRE_OFF  40624
#define SMEM_FLOATS 40640
#define SMEM_BYTES  (SMEM_FLOATS * 4)   // 162560 B <= 160 KiB

#define ROWS17(OP)                                                            \
  OP(0) OP(1) OP(2) OP(3) OP(4) OP(5) OP(6) OP(7) OP(8)                       \
  OP(9) OP(10) OP(11) OP(12) OP(13) OP(14) OP(15) OP(16)
#define ROWS15(OP)                                                            \
  OP(0) OP(1) OP(2) OP(3) OP(4) OP(5) OP(6) OP(7)                             \
  OP(8) OP(9) OP(10) OP(11) OP(12) OP(13) OP(14)
#define ROWS32(OP)                                                            \
  OP(0) OP(1) OP(2) OP(3) OP(4) OP(5) OP(6) OP(7)                             \
  OP(8) OP(9) OP(10) OP(11) OP(12) OP(13) OP(14) OP(15)                       \
  OP(16) OP(17) OP(18) OP(19) OP(20) OP(21) OP(22) OP(23)                     \
  OP(24) OP(25) OP(26) OP(27) OP(28) OP(29) OP(30) OP(31)

__device__ __forceinline__ float hsum8(f32x8 v) {
  return ((v.s0 + v.s1) + (v.s2 + v.s3)) + ((v.s4 + v.s5) + (v.s6 + v.s7));
}
__device__ __forceinline__ ushort f2bf(float f) {
  uint32 u = __float_as_uint(f);
  return (ushort)((u + 0x7FFFu + ((u >> 16) & 1u)) >> 16);
}
__device__ __forceinline__ float bf2f(ushort h) {
  return __uint_as_float(((uint32)h) << 16);
}
__device__ __forceinline__ float qreduce(float e) {
  e += __shfl_xor(e, 1);  e += __shfl_xor(e, 2);  e += __shfl_xor(e, 4);
  e += __shfl_xor(e, 8);  e += __shfl_xor(e, 16);
  return e;
}

#define FMA16(c, a, b)                                                        \
  c[0][0] += a.x * b.x; c[0][1] += a.x * b.y; c[0][2] += a.x * b.z; c[0][3] += a.x * b.w; \
  c[1][0] += a.y * b.x; c[1][1] += a.y * b.y; c[1][2] += a.y * b.z; c[1][3] += a.y * b.w; \
  c[2][0] += a.z * b.x; c[2][1] += a.z * b.y; c[2][2] += a.z * b.z; c[2][3] += a.z * b.w; \
  c[3][0] += a.w * b.x; c[3][1] += a.w * b.y; c[3][2] += a.w * b.z; c[3][3] += a.w * b.w;

// ---------------------------------------------------------------- k_gram ----
__global__ __launch_bounds__(256) void k_gram(const float* __restrict__ X,
                                              float* __restrict__ G) {
  const int bi = blockIdx.y, bj = blockIdx.x;
  if (bj > bi) return;
  __shared__ float Xa[32][68];
  __shared__ float Xb[32][68];
  const int tid = threadIdx.x;
  const int tx = tid & 15, ty = tid >> 4;
  float c[4][4] = {};
  for (int k0 = 0; k0 < 1024; k0 += 32) {
    __syncthreads();
    {
      const int row = tid >> 2, kk = (tid & 3) * 8;
      const float* pa = X + (bi * 64 + row) * 1024 + k0 + kk;
      const float4 a0 = *(const float4*)pa;
      const float4 a1 = *(const float4*)(pa + 4);
      Xa[kk + 0][row] = a0.x; Xa[kk + 1][row] = a0.y;
      Xa[kk + 2][row] = a0.z; Xa[kk + 3][row] = a0.w;
      Xa[kk + 4][row] = a1.x; Xa[kk + 5][row] = a1.y;
      Xa[kk + 6][row] = a1.z; Xa[kk + 7][row] = a1.w;
      const float* pb = X + (bj * 64 + row) * 1024 + k0 + kk;
      const float4 b0 = *(const float4*)pb;
      const float4 b1 = *(const float4*)(pb + 4);
      Xb[kk + 0][row] = b0.x; Xb[kk + 1][row] = b0.y;
      Xb[kk + 2][row] = b0.z; Xb[kk + 3][row] = b0.w;
      Xb[kk + 4][row] = b1.x; Xb[kk + 5][row] = b1.y;
      Xb[kk + 6][row] = b1.z; Xb[kk + 7][row] = b1.w;
    }
    __syncthreads();
#pragma unroll
    for (int kk = 0; kk < 32; kk++) {
      const float4 a = *(const float4*)&Xa[kk][ty * 4];
      const float4 b = *(const float4*)&Xb[kk][tx * 4];
      FMA16(c, a, b)
    }
  }
#pragma unroll
  for (int ii = 0; ii < 4; ii++) {
    *(float4*)(G + (bi * 64 + ty * 4 + ii) * 1024 + bj * 64 + tx * 4) =
        make_float4(c[ii][0], c[ii][1], c[ii][2], c[ii][3]);
  }
}

// ----------------------------------------------------------------- k_z10 ----
__global__ __launch_bounds__(256) void k_z10(const float* __restrict__ X,
                                             const float* __restrict__ W1g,
                                             float* __restrict__ Z10) {
  const int bi = blockIdx.y, bj = blockIdx.x;
  __shared__ float At[32][68];
  __shared__ float Bt[32][68];
  const int tid = threadIdx.x;
  const int tx = tid & 15, ty = tid >> 4;
  float c[4][4] = {};
  for (int k0 = 0; k0 < 1024; k0 += 32) {
    __syncthreads();
    {
      const int row = tid >> 2, kk = (tid & 3) * 8;
      const float* pa = X + (bi * 64 + row) * 1024 + k0 + kk;
      const float4 a0 = *(const float4*)pa;
      const float4 a1 = *(const float4*)(pa + 4);
      At[kk + 0][row] = a0.x; At[kk + 1][row] = a0.y;
      At[kk + 2][row] = a0.z; At[kk + 3][row] = a0.w;
      At[kk + 4][row] = a1.x; At[kk + 5][row] = a1.y;
      At[kk + 6][row] = a1.z; At[kk + 7][row] = a1.w;
      const int kr = tid >> 3, j8 = (tid & 7) * 8;
      const float* pb = W1g + (k0 + kr) * 256 + bj * 64 + j8;
      *(float4*)&Bt[kr][j8]     = *(const float4*)pb;
      *(float4*)&Bt[kr][j8 + 4] = *(const float4*)(pb + 4);
    }
    __syncthreads();
#pragma unroll
    for (int kk = 0; kk < 32; kk++) {
      const float4 a = *(const float4*)&At[kk][ty * 4];
      const float4 b = *(const float4*)&Bt[kk][tx * 4];
      FMA16(c, a, b)
    }
  }
#pragma unroll
  for (int ii = 0; ii < 4; ii++) {
    *(float4*)(Z10 + (bi * 64 + ty * 4 + ii) * 256 + bj * 64 + tx * 4) =
        make_float4(c[ii][0], c[ii][1], c[ii][2], c[ii][3]);
  }
}

// --------------------------------------------------------------- k_w1out ----
__global__ __launch_bounds__(256) void k_w1out(
    const float* __restrict__ X, const float* __restrict__ o1g,
    const float* __restrict__ cg, const float* __restrict__ W1g,
    const float* __restrict__ sclg, float* __restrict__ outW1) {
  const int bi = blockIdx.y, bj = blockIdx.x;
  __shared__ float At[32][68];
  __shared__ float Bt[32][68];
  const int tid = threadIdx.x;
  const int tx = tid & 15, ty = tid >> 4;
  float c[4][4] = {};
  for (int k0 = 0; k0 < 1024; k0 += 32) {
    __syncthreads();
    {
      const int kr = tid >> 3, m8 = (tid & 7) * 8;
      const float* pa = X + (k0 + kr) * 1024 + bi * 64 + m8;
      *(float4*)&At[kr][m8]     = *(const float4*)pa;
      *(float4*)&At[kr][m8 + 4] = *(const float4*)(pa + 4);
      const float cs = cg[k0 + kr];
      const float* pb = o1g + (k0 + kr) * 256 + bj * 64 + m8;
      float4 b0 = *(const float4*)pb;
      float4 b1 = *(const float4*)(pb + 4);
      b0.x *= cs; b0.y *= cs; b0.z *= cs; b0.w *= cs;
      b1.x *= cs; b1.y *= cs; b1.z *= cs; b1.w *= cs;
      *(float4*)&Bt[kr][m8]     = b0;
      *(float4*)&Bt[kr][m8 + 4] = b1;
    }
    __syncthreads();
#pragma unroll
    for (int kk = 0; kk < 32; kk++) {
      const float4 a = *(const float4*)&At[kk][ty * 4];
      const float4 b = *(const float4*)&Bt[kk][tx * 4];
      FMA16(c, a, b)
    }
  }
  const float s1f = sclg[0];
#pragma unroll
  for (int ii = 0; ii < 4; ii++) {
    const int row = bi * 64 + ty * 4 + ii;
    const float4 w = *(const float4*)(W1g + row * 256 + bj * 64 + tx * 4);
    *(float4*)(outW1 + row * 256 + bj * 64 + tx * 4) =
        make_float4(s1f * (w.x + c[ii][0]), s1f * (w.y + c[ii][1]),
                    s1f * (w.z + c[ii][2]), s1f * (w.w + c[ii][3]));
  }
}

// ---------------------------------------------------------------- k2_seq ----
__device__ __forceinline__ float block_reduce4(float v, float* tmp, int tid) {
#pragma unroll
  for (int off = 32; off > 0; off >>= 1) v += __shfl_xor(v, off);
  __syncthreads();
  if ((tid & 63) == 0) tmp[tid >> 6] = v;
  __syncthreads();
  const float s = tmp[0] + tmp[1] + tmp[2] + tmp[3];
  __syncthreads();
  return s;
}

__global__ __launch_bounds__(256) void k2_seq(
    const float* __restrict__ Tg, const float* __restrict__ W1g,
    const float* __restrict__ b1g, const float* __restrict__ W2g,
    const float* __restrict__ b2g, const float* __restrict__ W3g,
    const float* __restrict__ b3g, const float* __restrict__ G,
    const float* __restrict__ Z10, float* __restrict__ o1g,
    float* __restrict__ cg, float* __restrict__ z1pg,
    float* __restrict__ sclg, float* __restrict__ outW2,
    float* __restrict__ outW3) {
  extern __shared__ float sm[];
  const int tid = threadIdx.x;
  const int p = tid >> 5;  // 0..7
  const int q = tid & 31;  // 0..31

  // ---- persistent register state (named SSA only) ----
  f32x8 W2_0, W2_1, W2_2, W2_3, W2_4, W2_5, W2_6, W2_7, W2_8,
        W2_9, W2_10, W2_11, W2_12, W2_13, W2_14, W2_15, W2_16;
  float W3x_0, W3x_1, W3x_2, W3x_3, W3x_4, W3x_5, W3x_6, W3x_7,
        W3x_8, W3x_9, W3x_10, W3x_11, W3x_12, W3x_13, W3x_14, W3x_15,
        W3x_16, W3x_17, W3x_18, W3x_19, W3x_20, W3x_21, W3x_22, W3x_23,
        W3x_24, W3x_25, W3x_26, W3x_27, W3x_28, W3x_29, W3x_30, W3x_31;
  float W3y_0, W3y_1, W3y_2, W3y_3, W3y_4, W3y_5, W3y_6, W3y_7,
        W3y_8, W3y_9, W3y_10, W3y_11, W3y_12, W3y_13, W3y_14, W3y_15,
        W3y_16, W3y_17, W3y_18, W3y_19, W3y_20, W3y_21, W3y_22, W3y_23,
        W3y_24, W3y_25, W3y_26, W3y_27, W3y_28, W3y_29, W3y_30, W3y_31;

#define IW2(i) W2_##i = *(const f32x8*)(W2g + (p * 17 + i) * 256 + q * 8);
  ROWS17(IW2)
#define IW3(j)                                                                \
  { const int row = p * 32 + j;                                               \
    W3x_##j = W3g[row * 64 + q * 2];                                          \
    W3y_##j = W3g[row * 64 + q * 2 + 1]; }
  ROWS32(IW3)

  float acc2 = 0.f;
  // LDS W2 rows 136..255, split-half conflict-free layout.
#define IW2L(i)                                                               \
  { const int gr = p * 15 + i;                                                \
    const f32x8 tv = *(const f32x8*)(W2g + (136 + gr) * 256 + q * 8);         \
    *(float4*)(sm + W2LA_OFF + gr * 128 + q * 4) =                            \
        make_float4(tv.s0, tv.s1, tv.s2, tv.s3);                              \
    *(float4*)(sm + W2LB_OFF + gr * 128 + q * 4) =                            \
        make_float4(tv.s4, tv.s5, tv.s6, tv.s7);                              \
    const f32x8 t2 = tv * tv; acc2 += hsum8(t2); }
  ROWS15(IW2L)
#define N2R(i) { const f32x8 t2 = W2_##i * W2_##i; acc2 += hsum8(t2); }
  ROWS17(N2R)

  sm[B1V_OFF + tid] = b1g[tid];
  sm[B2V_OFF + tid] = b2g[tid];
  if (tid < 64) sm[B3V_OFF + tid] = b3g[tid];

  float acc1 = 0.f;
  for (int i = tid; i < 65536; i += 256) {
    const float4 v = ((const float4*)W1g)[i];
    acc1 += v.x * v.x + v.y * v.y + v.z * v.z + v.w * v.w;
  }
  __syncthreads();
  const float n1init = block_reduce4(acc1, sm + SCRB_OFF, tid);
  const float n2init = block_reduce4(acc2, sm + SCRB_OFF, tid);
  float acc3 = 0.f;
#define N3R(j) acc3 += W3x_##j * W3x_##j + W3y_##j * W3y_##j;
  ROWS32(N3R)
  const float n3init = block_reduce4(acc3, sm + SCRB_OFF, tid);

  float s1 = 1.f;
  double n1d = (double)n1init;
  float n2 = n2init, n3 = n3init;
  __syncthreads();

  for (int b = 0; b < 32; b++) {
    const int bs = b * 32;
    // ---- prefix (2 passes x 16 rows): z1pg[r] = Z10[bs+r] + sum cg*G*o1
    for (int v = 0; v < 2; v++) {
      f32x8 pacc0 = {0.f, 0.f, 0.f, 0.f, 0.f, 0.f, 0.f, 0.f};
      f32x8 pacc1 = pacc0;
      for (int c0 = 0; c0 < bs; c0 += 16) {
        __syncthreads();
#pragma unroll
        for (int u = 0; u < 4; u++) {
          const int fi = tid + u * 256;
          const int row = fi >> 6, c4 = fi & 63;
          *(float4*)(sm + O1STG_OFF + row * 264 + c4 * 4) =
              *(const float4*)(o1g + (c0 + row) * 256 + c4 * 4);
        }
        {
          const int rr = tid >> 4, s16 = tid & 15;
          sm[SCR3_OFF + rr * 17 + s16] =
              G[(bs + v * 16 + rr) * 1024 + c0 + s16];
        }
        if (tid < 16) sm[CPRE_OFF + tid] = cg[c0 + tid];
        __syncthreads();
#pragma unroll
        for (int ss = 0; ss < 16; ss++) {
          const float cs = sm[CPRE_OFF + ss];
          const f32x8 o8 = *(const f32x8*)(sm + O1STG_OFF + ss * 264 + q * 8);
          pacc0 += (sm[SCR3_OFF + (p * 2 + 0) * 17 + ss] * cs) * o8;
          pacc1 += (sm[SCR3_OFF + (p * 2 + 1) * 17 + ss] * cs) * o8;
        }
      }
      const int r0 = v * 16 + p * 2;
      *(f32x8*)(z1pg + r0 * 256 + q * 8) =
          *(const f32x8*)(Z10 + (bs + r0) * 256 + q * 8) + pacc0;
      *(f32x8*)(z1pg + (r0 + 1) * 256 + q * 8) =
          *(const f32x8*)(Z10 + (bs + r0 + 1) * 256 + q * 8) + pacc1;
    }
    __syncthreads();
    // prime slot 0
    sm[Z1PRE_OFF + tid] = z1pg[tid];
    if (tid < 32) sm[GPRE_OFF + tid] = G[bs * 1024 + bs + tid];
    if (tid >= 64 && tid < 128) sm[TPRE_OFF + tid - 64] = Tg[bs * 64 + tid - 64];
    __syncthreads();

    // ---- 32 sequential steps
    for (int l = 0; l < 32; l++) {
      const int t = bs + l;
      const int cur = l & 1, nxt = cur ^ 1;
      const float* z1cur = sm + Z1PRE_OFF + cur * 256;
      const float* gcur  = sm + GPRE_OFF + cur * 32;
      const float* tcur  = sm + TPRE_OFF + cur * 64;
      // A: z1u = z1p[l] + history; a1 = sigmoid(s1*z1u + b1)
      {
        const ushort* o1h = (const ushort*)(sm + O1STG_OFF);
        float a = 0.f;
        for (int lp = 0; lp < l; lp++)
          a += sm[CH_OFF + lp] * gcur[lp] * bf2f(o1h[lp * 264 + tid]);
        const float z1u = z1cur[tid] + a;
        sm[Z1V_OFF + tid] = z1u;
        sm[A1V_OFF + tid] =
            1.f / (1.f + expf(-(s1 * z1u + sm[B1V_OFF + tid])));
      }
      __syncthreads();
      // B1: z2 col-partials
      {
        f32x8 acc = {0.f, 0.f, 0.f, 0.f, 0.f, 0.f, 0.f, 0.f};
#define B1R(i) acc += sm[A1V_OFF + p * 17 + i] * W2_##i;
        ROWS17(B1R)
#define B1L(i)                                                                \
        { const int gr = p * 15 + i;                                          \
          const float a1x = sm[A1V_OFF + 136 + gr];                           \
          const float4 A4 = *(const float4*)(sm + W2LA_OFF + gr * 128 + q * 4); \
          const float4 B4 = *(const float4*)(sm + W2LB_OFF + gr * 128 + q * 4); \
          acc.s0 += a1x * A4.x; acc.s1 += a1x * A4.y;                         \
          acc.s2 += a1x * A4.z; acc.s3 += a1x * A4.w;                         \
          acc.s4 += a1x * B4.x; acc.s5 += a1x * B4.y;                         \
          acc.s6 += a1x * B4.z; acc.s7 += a1x * B4.w; }
        ROWS15(B1L)
        *(f32x8*)(sm + SCRB_OFF + p * 264 + q * 8) = acc;
      }
      __syncthreads();
      // B2: z2, a2
      {
        float s = 0.f;
#pragma unroll
        for (int pp = 0; pp < 8; pp++) s += sm[SCRB_OFF + pp * 264 + tid];
        sm[Z2V_OFF + tid] = s;
        sm[A2V_OFF + tid] = 1.f / (1.f + expf(-(s + sm[B2V_OFF + tid])));
      }
      __syncthreads();
      // C1: z3 partials
      {
        float c0a = 0.f, c1a = 0.f;
#define C1R(j)                                                                \
        { const float a2x = sm[A2V_OFF + p * 32 + j];                         \
          c0a += a2x * W3x_##j; c1a += a2x * W3y_##j; }
        ROWS32(C1R)
        sm[SCR3_OFF + (q * 2 + 0) * 9 + p] = c0a;
        sm[SCR3_OFF + (q * 2 + 1) * 9 + p] = c1a;
      }
      __syncthreads();
      // C2 (wave 0) + prefetch next z1p/G-row/targets (waves 1-3)
      if (tid < 64) {
        float s = 0.f;
#pragma unroll
        for (int pp = 0; pp < 8; pp++) s += sm[SCR3_OFF + tid * 9 + pp];
        sm[Z3V_OFF + tid] = s;
        const float a3 = 1.f / (1.f + expf(-(s + sm[B3V_OFF + tid])));
        const float e = expf(-a3);
        float tot = e;
#pragma unroll
        for (int off = 32; off > 0; off >>= 1) tot += __shfl_xor(tot, off);
        const float outv = e / tot;
        const float d3 = (tcur[tid] - outv) * a3 * (1.f - a3);
        sm[D3V_OFF + tid] = d3;
        sm[B3V_OFF + tid] -= LRC * d3;
      } else if (tid < 128) {
        const int lane = tid - 64, ln = (l + 1 < 32) ? l + 1 : 31;
#pragma unroll
        for (int u = 0; u < 4; u++)
          sm[Z1PRE_OFF + nxt * 256 + lane + u * 64] =
              z1pg[ln * 256 + lane + u * 64];
      } else if (tid < 192) {
        const int lane = tid - 128, ln = (l + 1 < 32) ? l + 1 : 31;
        if (lane < 32)
          sm[GPRE_OFF + nxt * 32 + lane] = G[(bs + ln) * 1024 + bs + lane];
      } else {
        const int lane = tid - 192, ln = (l + 1 < 32) ? l + 1 : 31;
        sm[TPRE_OFF + nxt * 64 + lane] = Tg[(bs + ln) * 64 + lane];
      }
      __syncthreads();
      // E: o2 rows via full q-shuffle-reduce (owner lane q==0 writes)
      {
        const float d0 = sm[D3V_OFF + q * 2], d1 = sm[D3V_OFF + q * 2 + 1];
#define EROW(j)                                                               \
        { float e = W3x_##j * d0 + W3y_##j * d1;                              \
          e = qreduce(e);                                                     \
          if (q == 0) {                                                       \
            const int r = p * 32 + j;                                         \
            const float a2x = sm[A2V_OFF + r];                                \
            const float o2 = e * a2x * (1.f - a2x);                           \
            sm[O2V_OFF + r] = o2;                                             \
            sm[B2V_OFF + r] -= LRC * o2; } }
        ROWS32(EROW)
      }
      __syncthreads();
      // F: o1 rows via q-shuffle-reduce (reg rows + LDS rows)
      {
        const f32x8 ov8 = *(const f32x8*)(sm + O2V_OFF + q * 8);
#define FROWR(i)                                                              \
        { const f32x8 tmp = W2_##i * ov8; float e = hsum8(tmp);               \
          e = qreduce(e);                                                     \
          if (q == 0) {                                                       \
            const int r = p * 17 + i;                                         \
            const float a1x = sm[A1V_OFF + r];                                \
            const float o1x = e * a1x * (1.f - a1x);                          \
            sm[O1V_OFF + r] = o1x;                                            \
            sm[B1V_OFF + r] -= LRC * o1x; } }
        ROWS17(FROWR)
#define FROWL(i)                                                              \
        { const int gr = p * 15 + i;                                          \
          const float4 A4 = *(const float4*)(sm + W2LA_OFF + gr * 128 + q * 4); \
          const float4 B4 = *(const float4*)(sm + W2LB_OFF + gr * 128 + q * 4); \
          float e = A4.x * ov8.s0 + A4.y * ov8.s1 + A4.z * ov8.s2 +           \
                    A4.w * ov8.s3 + B4.x * ov8.s4 + B4.y * ov8.s5 +           \
                    B4.z * ov8.s6 + B4.w * ov8.s7;                            \
          e = qreduce(e);                                                     \
          if (q == 0) {                                                       \
            const int r = 136 + gr;                                           \
            const float a1x = sm[A1V_OFF + r];                                \
            const float o1x = e * a1x * (1.f - a1x);                          \
            sm[O1V_OFF + r] = o1x;                                            \
            sm[B1V_OFF + r] -= LRC * o1x; } }
        ROWS15(FROWL)
      }
      __syncthreads();
      // G: batched dots (3 rounds over 4 waves) + o1 copy-out (wave 3, r2)
      {
        const int w = tid >> 6, lane = tid & 63;
        {
          float v = 0.f;
          if (w == 0)      { for (int i = lane; i < 256; i += 64) v += sm[Z1V_OFF+i] * sm[O1V_OFF+i]; }
          else if (w == 1) { for (int i = lane; i < 256; i += 64) v += sm[O1V_OFF+i] * sm[O1V_OFF+i]; }
          else if (w == 2) { for (int i = lane; i < 256; i += 64) v += sm[Z2V_OFF+i] * sm[O2V_OFF+i]; }
          else             { for (int i = lane; i < 256; i += 64) v += sm[A1V_OFF+i] * sm[A1V_OFF+i]; }
#pragma unroll
          for (int off = 32; off > 0; off >>= 1) v += __shfl_xor(v, off);
          if (lane == 0) sm[DTS_OFF + w] = v;
        }
        {
          float v = 0.f;
          if (w == 0)      { for (int i = lane; i < 256; i += 64) v += sm[O2V_OFF+i] * sm[O2V_OFF+i]; }
          else if (w == 1) { v = sm[Z3V_OFF+lane] * sm[D3V_OFF+lane]; }
          else if (w == 2) { for (int i = lane; i < 256; i += 64) v += sm[A2V_OFF+i] * sm[A2V_OFF+i]; }
          else             { v = sm[D3V_OFF+lane] * sm[D3V_OFF+lane]; }
#pragma unroll
          for (int off = 32; off > 0; off >>= 1) v += __shfl_xor(v, off);
          if (lane == 0) sm[DTS_OFF + 4 + w] = v;
        }
        if (w == 3) {
          ushort* o1h = (ushort*)(sm + O1STG_OFF);
          for (int i = lane; i < 256; i += 64) {
            const float x = sm[O1V_OFF + i];
            o1g[t * 256 + i] = x;
            o1h[l * 264 + i] = f2bf(x);
          }
        } else {
          float v = 0.f;
          if (w == 0)      { for (int i = lane; i < 256; i += 64) v += sm[B1V_OFF+i] * sm[B1V_OFF+i]; }
          else if (w == 1) { for (int i = lane; i < 256; i += 64) v += sm[B2V_OFF+i] * sm[B2V_OFF+i]; }
          else             { v = sm[B3V_OFF+lane] * sm[B3V_OFF+lane]; }
#pragma unroll
          for (int off = 32; off > 0; off >>= 1) v += __shfl_xor(v, off);
          if (lane == 0) sm[DTS_OFF + 8 + w] = v;
        }
      }
      __syncthreads();
      // H: replicated recurrences + rank-1 updates + renorm
      {
        const float c1 = -LRC / s1;
        const double gtt = (double)gcur[l];
        const double n1 = n1d + 2.0 * (double)c1 * (double)sm[DTS_OFF + 0] +
                          (double)c1 * (double)c1 * gtt * (double)sm[DTS_OFF + 1];
        n1d = n1;
        const double w1n = (double)s1 * sqrt(n1);
        s1 = (float)((double)s1 / fmax(w1n, (double)EPSV));
        if (tid == 0) { sm[CH_OFF + l] = c1; cg[t] = c1; }
        const float n2p = n2 - 2.f * LRC * sm[DTS_OFF + 2] +
                          LRC * LRC * sm[DTS_OFF + 3] * sm[DTS_OFF + 4];
        const float r2s = 1.f / fmaxf(sqrtf(n2p), EPSV);
        n2 = n2p * r2s * r2s;
        const float n3p = n3 - 2.f * LRC * sm[DTS_OFF + 5] +
                          LRC * LRC * sm[DTS_OFF + 6] * sm[DTS_OFF + 7];
        const float r3s = 1.f / fmaxf(sqrtf(n3p), EPSV);
        n3 = n3p * r3s * r3s;
        const float rb1 = 1.f / fmaxf(sqrtf(sm[DTS_OFF + 8]), EPSV);
        const float rb2 = 1.f / fmaxf(sqrtf(sm[DTS_OFF + 9]), EPSV);
        const float rb3 = 1.f / fmaxf(sqrtf(sm[DTS_OFF + 10]), EPSV);

        const f32x8 ovs = (-LRC * r2s) * (*(const f32x8*)(sm + O2V_OFF + q * 8));
        const float4 ovlo = make_float4(ovs.s0, ovs.s1, ovs.s2, ovs.s3);
        const float4 ovhi = make_float4(ovs.s4, ovs.s5, ovs.s6, ovs.s7);
#define HR(i)                                                                 \
        { const float a1x = sm[A1V_OFF + p * 17 + i];                         \
          W2_##i = W2_##i * r2s + a1x * ovs; }
        ROWS17(HR)
#define HL(i)                                                                 \
        { const int gr = p * 15 + i;                                          \
          const float a1x = sm[A1V_OFF + 136 + gr];                           \
          float4* pa4 = (float4*)(sm + W2LA_OFF + gr * 128 + q * 4);          \
          float4* pb4 = (float4*)(sm + W2LB_OFF + gr * 128 + q * 4);          \
          float4 A4 = *pa4; float4 B4 = *pb4;                                 \
          A4.x = A4.x * r2s + a1x * ovlo.x; A4.y = A4.y * r2s + a1x * ovlo.y; \
          A4.z = A4.z * r2s + a1x * ovlo.z; A4.w = A4.w * r2s + a1x * ovlo.w; \
          B4.x = B4.x * r2s + a1x * ovhi.x; B4.y = B4.y * r2s + a1x * ovhi.y; \
          B4.z = B4.z * r2s + a1x * ovhi.z; B4.w = B4.w * r2s + a1x * ovhi.w; \
          *pa4 = A4; *pb4 = B4; }
        ROWS15(HL)
        const float d0s = -LRC * r3s * sm[D3V_OFF + q * 2];
        const float d1s = -LRC * r3s * sm[D3V_OFF + q * 2 + 1];
#define HW3(j)                                                                \
        { const float a2x = sm[A2V_OFF + p * 32 + j];                         \
          W3x_##j = W3x_##j * r3s + a2x * d0s;                                \
          W3y_##j = W3y_##j * r3s + a2x * d1s; }
        ROWS32(HW3)
        sm[B1V_OFF + tid] *= rb1;
        sm[B2V_OFF + tid] *= rb2;
        if (tid < 64) sm[B3V_OFF + tid] *= rb3;
      }
      __syncthreads();
    }
  }

  if (tid == 0) sclg[0] = s1;
#define OW2(i) *(f32x8*)(outW2 + (p * 17 + i) * 256 + q * 8) = W2_##i;
  ROWS17(OW2)
#define OW2L(i)                                                               \
  { const int gr = p * 15 + i;                                                \
    const float4 A4 = *(const float4*)(sm + W2LA_OFF + gr * 128 + q * 4);     \
    const float4 B4 = *(const float4*)(sm + W2LB_OFF + gr * 128 + q * 4);     \
    *(float4*)(outW2 + (136 + gr) * 256 + q * 8) = A4;                        \
    *(float4*)(outW2 + (136 + gr) * 256 + q * 8 + 4) = B4; }
  ROWS15(OW2L)
#define OW3(j)                                                                \
  { const int row = p * 32 + j;                                               \
    outW3[row * 64 + q * 2] = W3x_##j;                                        \
    outW3[row * 64 + q * 2 + 1] = W3y_##j; }
  ROWS32(OW3)
}

// ---------------------------------------------------------------- launch ----
extern "C" void kernel_launch(void* const* d_in, const int* in_sizes, int n_in,
                              void* d_out, int out_size, void* d_ws,
                              size_t ws_size, hipStream_t stream) {
  (void)in_sizes; (void)n_in; (void)out_size; (void)ws_size;
  const float* X   = (const float*)d_in[0];
  const float* Tg  = (const float*)d_in[1];
  const float* W1g = (const float*)d_in[2];
  const float* b1g = (const float*)d_in[3];
  const float* W2g = (const float*)d_in[4];
  const float* b2g = (const float*)d_in[5];
  const float* W3g = (const float*)d_in[6];
  const float* b3g = (const float*)d_in[7];
  float* out = (float*)d_out;
  float* ws  = (float*)d_ws;

  float* G    = ws;                  // 1048576
  float* Z10  = G + 1048576;         // 262144
  float* o1g  = Z10 + 262144;        // 262144
  float* cg   = o1g + 262144;        // 1024
  float* sclg = cg + 1024;           // 8
  float* z1pg = sclg + 8;            // 8192

  (void)hipFuncSetAttribute((const void*)k2_seq,
                            hipFuncAttributeMaxDynamicSharedMemorySize,
                            SMEM_BYTES);

  k_gram<<<dim3(16, 16), 256, 0, stream>>>(X, G);
  k_z10<<<dim3(4, 16), 256, 0, stream>>>(X, W1g, Z10);
  k2_seq<<<dim3(1), dim3(256), SMEM_BYTES, stream>>>(
      Tg, W1g, b1g, W2g, b2g, W3g, b3g, G, Z10, o1g, cg, z1pg, sclg,
      out + 262144, out + 327680);
  k_w1out<<<dim3(4, 16), 256, 0, stream>>>(X, o1g, cg, W1g, sclg, out);
}

// Round 10
// 38598.581 us; speedup vs baseline: 1.0607x; 1.0607x over previous
//
#include <hip/hip_runtime.h>
#include <math.h>

// Backprop_29188597744223 — 1024-step sequential MLP training scan.
//
//   k2_seq: ONE workgroup, 512 threads (8 waves = 2/SIMD: latency hiding,
//           proven necessary by R9's 1-wave/SIMD 41ms disaster). VGPR rule
//           (R2-R9): budget = 65536/threads = 128. Persistent state sized to
//           fit: W2 rows 0..143 in regs (9 f32x8), rows 144..255 in LDS fp32
//           split-plane q*4 layout (bank-uniform, verified R9), W3 16x2 in
//           regs. o1 history bf16. 32-step blocks, Gram trick for W1.

#define LRC  0.01f
#define EPSV 1e-8f

typedef float f32x8 __attribute__((ext_vector_type(8)));
typedef unsigned int uint32;
typedef unsigned short ushort;

// ---- LDS layout (float offsets), total 38544 floats = 154176 B ----
#define W2LA_OFF  0        // [112][128]
#define W2LB_OFF  14336    // [112][128]
#define O1H_OFF   28672    // o1h bf16 [32][264]ush / prefix stage fp32 [16][264]
#define SCRB_OFF  32896    // [8][258]
#define SCR3_OFF  34960    // [64][9] steps / [16][17] prefix G
#define Z1PRE_OFF 35536    // [2][256]
#define GPRE_OFF  36048    // [2][32]
#define TPRE_OFF  36112    // [2][64]
#define A1V_OFF   36240
#define Z1V_OFF   36496
#define Z2V_OFF   36752
#define A2V_OFF   37008
#define O2V_OFF   37264
#define O1V_OFF   37520
#define B1V_OFF   37776
#define B2V_OFF   38032
#define Z3V_OFF   38288
#define D3V_OFF   38352
#define B3V_OFF   38416
#define CH_OFF    38480
#define DTS_OFF   38512
#define CPRE_OFF  38528
#define SMEM_FLOATS 38544
#define SMEM_BYTES  (SMEM_FLOATS * 4)

#define ROWS9(OP)  OP(0) OP(1) OP(2) OP(3) OP(4) OP(5) OP(6) OP(7) OP(8)
#define ROWS7(OP)  OP(0) OP(1) OP(2) OP(3) OP(4) OP(5) OP(6)
#define ROWS16(OP)                                                            \
  OP(0) OP(1) OP(2) OP(3) OP(4) OP(5) OP(6) OP(7)                             \
  OP(8) OP(9) OP(10) OP(11) OP(12) OP(13) OP(14) OP(15)

__device__ __forceinline__ float hsum8(f32x8 v) {
  return ((v.s0 + v.s1) + (v.s2 + v.s3)) + ((v.s4 + v.s5) + (v.s6 + v.s7));
}
__device__ __forceinline__ ushort f2bf(float f) {
  uint32 u = __float_as_uint(f);
  return (ushort)((u + 0x7FFFu + ((u >> 16) & 1u)) >> 16);
}
__device__ __forceinline__ float bf2f(ushort h) {
  return __uint_as_float(((uint32)h) << 16);
}
__device__ __forceinline__ float qreduce(float e) {
  e += __shfl_xor(e, 1);  e += __shfl_xor(e, 2);  e += __shfl_xor(e, 4);
  e += __shfl_xor(e, 8);  e += __shfl_xor(e, 16);
  return e;
}

#define FMA16(c, a, b)                                                        \
  c[0][0] += a.x * b.x; c[0][1] += a.x * b.y; c[0][2] += a.x * b.z; c[0][3] += a.x * b.w; \
  c[1][0] += a.y * b.x; c[1][1] += a.y * b.y; c[1][2] += a.y * b.z; c[1][3] += a.y * b.w; \
  c[2][0] += a.z * b.x; c[2][1] += a.z * b.y; c[2][2] += a.z * b.z; c[2][3] += a.z * b.w; \
  c[3][0] += a.w * b.x; c[3][1] += a.w * b.y; c[3][2] += a.w * b.z; c[3][3] += a.w * b.w;

// ---------------------------------------------------------------- k_gram ----
__global__ __launch_bounds__(256) void k_gram(const float* __restrict__ X,
                                              float* __restrict__ G) {
  const int bi = blockIdx.y, bj = blockIdx.x;
  if (bj > bi) return;
  __shared__ float Xa[32][68];
  __shared__ float Xb[32][68];
  const int tid = threadIdx.x;
  const int tx = tid & 15, ty = tid >> 4;
  float c[4][4] = {};
  for (int k0 = 0; k0 < 1024; k0 += 32) {
    __syncthreads();
    {
      const int row = tid >> 2, kk = (tid & 3) * 8;
      const float* pa = X + (bi * 64 + row) * 1024 + k0 + kk;
      const float4 a0 = *(const float4*)pa;
      const float4 a1 = *(const float4*)(pa + 4);
      Xa[kk + 0][row] = a0.x; Xa[kk + 1][row] = a0.y;
      Xa[kk + 2][row] = a0.z; Xa[kk + 3][row] = a0.w;
      Xa[kk + 4][row] = a1.x; Xa[kk + 5][row] = a1.y;
      Xa[kk + 6][row] = a1.z; Xa[kk + 7][row] = a1.w;
      const float* pb = X + (bj * 64 + row) * 1024 + k0 + kk;
      const float4 b0 = *(const float4*)pb;
      const float4 b1 = *(const float4*)(pb + 4);
      Xb[kk + 0][row] = b0.x; Xb[kk + 1][row] = b0.y;
      Xb[kk + 2][row] = b0.z; Xb[kk + 3][row] = b0.w;
      Xb[kk + 4][row] = b1.x; Xb[kk + 5][row] = b1.y;
      Xb[kk + 6][row] = b1.z; Xb[kk + 7][row] = b1.w;
    }
    __syncthreads();
#pragma unroll
    for (int kk = 0; kk < 32; kk++) {
      const float4 a = *(const float4*)&Xa[kk][ty * 4];
      const float4 b = *(const float4*)&Xb[kk][tx * 4];
      FMA16(c, a, b)
    }
  }
#pragma unroll
  for (int ii = 0; ii < 4; ii++) {
    *(float4*)(G + (bi * 64 + ty * 4 + ii) * 1024 + bj * 64 + tx * 4) =
        make_float4(c[ii][0], c[ii][1], c[ii][2], c[ii][3]);
  }
}

// ----------------------------------------------------------------- k_z10 ----
__global__ __launch_bounds__(256) void k_z10(const float* __restrict__ X,
                                             const float* __restrict__ W1g,
                                             float* __restrict__ Z10) {
  const int bi = blockIdx.y, bj = blockIdx.x;
  __shared__ float At[32][68];
  __shared__ float Bt[32][68];
  const int tid = threadIdx.x;
  const int tx = tid & 15, ty = tid >> 4;
  float c[4][4] = {};
  for (int k0 = 0; k0 < 1024; k0 += 32) {
    __syncthreads();
    {
      const int row = tid >> 2, kk = (tid & 3) * 8;
      const float* pa = X + (bi * 64 + row) * 1024 + k0 + kk;
      const float4 a0 = *(const float4*)pa;
      const float4 a1 = *(const float4*)(pa + 4);
      At[kk + 0][row] = a0.x; At[kk + 1][row] = a0.y;
      At[kk + 2][row] = a0.z; At[kk + 3][row] = a0.w;
      At[kk + 4][row] = a1.x; At[kk + 5][row] = a1.y;
      At[kk + 6][row] = a1.z; At[kk + 7][row] = a1.w;
      const int kr = tid >> 3, j8 = (tid & 7) * 8;
      const float* pb = W1g + (k0 + kr) * 256 + bj * 64 + j8;
      *(float4*)&Bt[kr][j8]     = *(const float4*)pb;
      *(float4*)&Bt[kr][j8 + 4] = *(const float4*)(pb + 4);
    }
    __syncthreads();
#pragma unroll
    for (int kk = 0; kk < 32; kk++) {
      const float4 a = *(const float4*)&At[kk][ty * 4];
      const float4 b = *(const float4*)&Bt[kk][tx * 4];
      FMA16(c, a, b)
    }
  }
#pragma unroll
  for (int ii = 0; ii < 4; ii++) {
    *(float4*)(Z10 + (bi * 64 + ty * 4 + ii) * 256 + bj * 64 + tx * 4) =
        make_float4(c[ii][0], c[ii][1], c[ii][2], c[ii][3]);
  }
}

// --------------------------------------------------------------- k_w1out ----
__global__ __launch_bounds__(256) void k_w1out(
    const float* __restrict__ X, const float* __restrict__ o1g,
    const float* __restrict__ cg, const float* __restrict__ W1g,
    const float* __restrict__ sclg, float* __restrict__ outW1) {
  const int bi = blockIdx.y, bj = blockIdx.x;
  __shared__ float At[32][68];
  __shared__ float Bt[32][68];
  const int tid = threadIdx.x;
  const int tx = tid & 15, ty = tid >> 4;
  float c[4][4] = {};
  for (int k0 = 0; k0 < 1024; k0 += 32) {
    __syncthreads();
    {
      const int kr = tid >> 3, m8 = (tid & 7) * 8;
      const float* pa = X + (k0 + kr) * 1024 + bi * 64 + m8;
      *(float4*)&At[kr][m8]     = *(const float4*)pa;
      *(float4*)&At[kr][m8 + 4] = *(const float4*)(pa + 4);
      const float cs = cg[k0 + kr];
      const float* pb = o1g + (k0 + kr) * 256 + bj * 64 + m8;
      float4 b0 = *(const float4*)pb;
      float4 b1 = *(const float4*)(pb + 4);
      b0.x *= cs; b0.y *= cs; b0.z *= cs; b0.w *= cs;
      b1.x *= cs; b1.y *= cs; b1.z *= cs; b1.w *= cs;
      *(float4*)&Bt[kr][m8]     = b0;
      *(float4*)&Bt[kr][m8 + 4] = b1;
    }
    __syncthreads();
#pragma unroll
    for (int kk = 0; kk < 32; kk++) {
      const float4 a = *(const float4*)&At[kk][ty * 4];
      const float4 b = *(const float4*)&Bt[kk][tx * 4];
      FMA16(c, a, b)
    }
  }
  const float s1f = sclg[0];
#pragma unroll
  for (int ii = 0; ii < 4; ii++) {
    const int row = bi * 64 + ty * 4 + ii;
    const float4 w = *(const float4*)(W1g + row * 256 + bj * 64 + tx * 4);
    *(float4*)(outW1 + row * 256 + bj * 64 + tx * 4) =
        make_float4(s1f * (w.x + c[ii][0]), s1f * (w.y + c[ii][1]),
                    s1f * (w.z + c[ii][2]), s1f * (w.w + c[ii][3]));
  }
}

// ---------------------------------------------------------------- k2_seq ----
__device__ __forceinline__ float block_reduce8(float v, float* tmp, int tid) {
#pragma unroll
  for (int off = 32; off > 0; off >>= 1) v += __shfl_xor(v, off);
  __syncthreads();
  if ((tid & 63) == 0) tmp[tid >> 6] = v;
  __syncthreads();
  float s = 0.f;
#pragma unroll
  for (int w = 0; w < 8; w++) s += tmp[w];
  __syncthreads();
  return s;
}

__global__ __launch_bounds__(512) void k2_seq(
    const float* __restrict__ Tg, const float* __restrict__ W1g,
    const float* __restrict__ b1g, const float* __restrict__ W2g,
    const float* __restrict__ b2g, const float* __restrict__ W3g,
    const float* __restrict__ b3g, const float* __restrict__ G,
    const float* __restrict__ Z10, float* __restrict__ o1g,
    float* __restrict__ cg, float* __restrict__ z1pg,
    float* __restrict__ sclg, float* __restrict__ outW2,
    float* __restrict__ outW3) {
  extern __shared__ float sm[];
  const int tid = threadIdx.x;
  const int p = tid >> 5;  // 0..15
  const int q = tid & 31;  // 0..31
  const int w = tid >> 6;  // wave 0..7

  // ---- persistent register state (named SSA; 109 floats) ----
  f32x8 W2_0, W2_1, W2_2, W2_3, W2_4, W2_5, W2_6, W2_7, W2_8;
  float W3x_0, W3x_1, W3x_2, W3x_3, W3x_4, W3x_5, W3x_6, W3x_7,
        W3x_8, W3x_9, W3x_10, W3x_11, W3x_12, W3x_13, W3x_14, W3x_15;
  float W3y_0, W3y_1, W3y_2, W3y_3, W3y_4, W3y_5, W3y_6, W3y_7,
        W3y_8, W3y_9, W3y_10, W3y_11, W3y_12, W3y_13, W3y_14, W3y_15;

#define IW2(i) W2_##i = *(const f32x8*)(W2g + (p * 9 + i) * 256 + q * 8);
  ROWS9(IW2)
#define IW3(j)                                                                \
  { const int row = p * 16 + j;                                               \
    W3x_##j = W3g[row * 64 + q * 2];                                          \
    W3y_##j = W3g[row * 64 + q * 2 + 1]; }
  ROWS16(IW3)

  float acc2 = 0.f;
  // LDS W2 rows 144..255 (7/p-group), split-plane q*4 (bank-uniform).
#define IW2L(i)                                                               \
  { const int gr = p * 7 + i;                                                 \
    const f32x8 tv = *(const f32x8*)(W2g + (144 + gr) * 256 + q * 8);         \
    *(float4*)(sm + W2LA_OFF + gr * 128 + q * 4) =                            \
        make_float4(tv.s0, tv.s1, tv.s2, tv.s3);                              \
    *(float4*)(sm + W2LB_OFF + gr * 128 + q * 4) =                            \
        make_float4(tv.s4, tv.s5, tv.s6, tv.s7);                              \
    const f32x8 t2 = tv * tv; acc2 += hsum8(t2); }
  ROWS7(IW2L)
#define N2R(i) { const f32x8 t2 = W2_##i * W2_##i; acc2 += hsum8(t2); }
  ROWS9(N2R)

  if (tid < 256) { sm[B1V_OFF + tid] = b1g[tid]; sm[B2V_OFF + tid] = b2g[tid]; }
  if (tid < 64) sm[B3V_OFF + tid] = b3g[tid];

  float acc1 = 0.f;
  for (int i = tid; i < 65536; i += 512) {
    const float4 v = ((const float4*)W1g)[i];
    acc1 += v.x * v.x + v.y * v.y + v.z * v.z + v.w * v.w;
  }
  __syncthreads();
  const float n1init = block_reduce8(acc1, sm + SCRB_OFF, tid);
  const float n2init = block_reduce8(acc2, sm + SCRB_OFF, tid);
  float acc3 = 0.f;
#define N3R(j) acc3 += W3x_##j * W3x_##j + W3y_##j * W3y_##j;
  ROWS16(N3R)
  const float n3init = block_reduce8(acc3, sm + SCRB_OFF, tid);

  float s1 = 1.f;
  double n1d = (double)n1init;
  float n2 = n2init, n3 = n3init;
  __syncthreads();

  for (int b = 0; b < 32; b++) {
    const int bs = b * 32;
    // ---- prefix (2 passes x 16 rows): z1pg[r] = Z10[bs+r] + sum cg*G*o1
    for (int v = 0; v < 2; v++) {
      f32x8 pacc = {0.f, 0.f, 0.f, 0.f, 0.f, 0.f, 0.f, 0.f};
      const int rv = v * 16 + p;
      for (int c0 = 0; c0 < bs; c0 += 16) {
        __syncthreads();
#pragma unroll
        for (int u = 0; u < 2; u++) {
          const int fi = tid + u * 512;            // 1024 float4s = 16x256
          const int row = fi >> 6, c4 = fi & 63;
          *(float4*)(sm + O1H_OFF + row * 264 + c4 * 4) =
              *(const float4*)(o1g + (c0 + row) * 256 + c4 * 4);
        }
        if (tid < 256) {
          const int rr = tid >> 4, s16 = tid & 15;
          sm[SCR3_OFF + rr * 17 + s16] =
              G[(bs + v * 16 + rr) * 1024 + c0 + s16];
        }
        if (tid < 16) sm[CPRE_OFF + tid] = cg[c0 + tid];
        __syncthreads();
#pragma unroll
        for (int ss = 0; ss < 16; ss++) {
          const float g = sm[SCR3_OFF + p * 17 + ss] * sm[CPRE_OFF + ss];
          pacc += g * (*(const f32x8*)(sm + O1H_OFF + ss * 264 + q * 8));
        }
      }
      *(f32x8*)(z1pg + rv * 256 + q * 8) =
          *(const f32x8*)(Z10 + (bs + rv) * 256 + q * 8) + pacc;
    }
    __syncthreads();
    // prime slot 0
    if (tid < 256) sm[Z1PRE_OFF + tid] = z1pg[tid];
    else if (tid < 288) sm[GPRE_OFF + tid - 256] = G[bs * 1024 + bs + tid - 256];
    else if (tid < 352) sm[TPRE_OFF + tid - 288] = Tg[bs * 64 + tid - 288];
    __syncthreads();

    // ---- 32 sequential steps
    for (int l = 0; l < 32; l++) {
      const int t = bs + l;
      const int cur = l & 1, nxt = cur ^ 1;
      const float* z1cur = sm + Z1PRE_OFF + cur * 256;
      const float* gcur  = sm + GPRE_OFF + cur * 32;
      const float* tcur  = sm + TPRE_OFF + cur * 64;
      // A: z1u = z1p[l] + history (bf16, 2 thr/col); a1 = sigmoid
      {
        const int j = tid >> 1, half = tid & 1;
        const ushort* o1h = (const ushort*)(sm + O1H_OFF);
        float a = 0.f;
        for (int lp = half; lp < l; lp += 2)
          a += sm[CH_OFF + lp] * gcur[lp] * bf2f(o1h[lp * 264 + j]);
        a += __shfl_xor(a, 1);
        if (half == 0) {
          const float z1u = z1cur[j] + a;
          sm[Z1V_OFF + j] = z1u;
          sm[A1V_OFF + j] =
              1.f / (1.f + expf(-(s1 * z1u + sm[B1V_OFF + j])));
        }
      }
      __syncthreads();
      // B1: z2 col-partials (9 reg + 7 LDS rows), wave-internal combine
      {
        f32x8 acc = {0.f, 0.f, 0.f, 0.f, 0.f, 0.f, 0.f, 0.f};
#define B1R(i) acc += sm[A1V_OFF + p * 9 + i] * W2_##i;
        ROWS9(B1R)
#define B1L(i)                                                                \
        { const int gr = p * 7 + i;                                           \
          const float a1x = sm[A1V_OFF + 144 + gr];                           \
          const float4 A4 = *(const float4*)(sm + W2LA_OFF + gr * 128 + q * 4); \
          const float4 B4 = *(const float4*)(sm + W2LB_OFF + gr * 128 + q * 4); \
          acc.s0 += a1x * A4.x; acc.s1 += a1x * A4.y;                         \
          acc.s2 += a1x * A4.z; acc.s3 += a1x * A4.w;                         \
          acc.s4 += a1x * B4.x; acc.s5 += a1x * B4.y;                         \
          acc.s6 += a1x * B4.z; acc.s7 += a1x * B4.w; }
        ROWS7(B1L)
        acc.s0 += __shfl_xor(acc.s0, 32); acc.s1 += __shfl_xor(acc.s1, 32);
        acc.s2 += __shfl_xor(acc.s2, 32); acc.s3 += __shfl_xor(acc.s3, 32);
        acc.s4 += __shfl_xor(acc.s4, 32); acc.s5 += __shfl_xor(acc.s5, 32);
        acc.s6 += __shfl_xor(acc.s6, 32); acc.s7 += __shfl_xor(acc.s7, 32);
        if ((tid & 32) == 0) *(f32x8*)(sm + SCRB_OFF + w * 258 + q * 8) = acc;
      }
      __syncthreads();
      // B2
      if (tid < 256) {
        float s = 0.f;
#pragma unroll
        for (int ww = 0; ww < 8; ww++) s += sm[SCRB_OFF + ww * 258 + tid];
        sm[Z2V_OFF + tid] = s;
        sm[A2V_OFF + tid] = 1.f / (1.f + expf(-(s + sm[B2V_OFF + tid])));
      }
      __syncthreads();
      // C1: z3 partials (16 W3 rows), wave-internal combine
      {
        float c0a = 0.f, c1a = 0.f;
#define C1R(j)                                                                \
        { const float a2x = sm[A2V_OFF + p * 16 + j];                         \
          c0a += a2x * W3x_##j; c1a += a2x * W3y_##j; }
        ROWS16(C1R)
        c0a += __shfl_xor(c0a, 32);
        c1a += __shfl_xor(c1a, 32);
        if ((tid & 32) == 0) {
          sm[SCR3_OFF + (q * 2 + 0) * 9 + w] = c0a;
          sm[SCR3_OFF + (q * 2 + 1) * 9 + w] = c1a;
        }
      }
      __syncthreads();
      // C2 (wave 0) + prefetch next z1p/G-row/targets (waves 1-3)
      if (tid < 64) {
        float s = 0.f;
#pragma unroll
        for (int ww = 0; ww < 8; ww++) s += sm[SCR3_OFF + tid * 9 + ww];
        sm[Z3V_OFF + tid] = s;
        const float a3 = 1.f / (1.f + expf(-(s + sm[B3V_OFF + tid])));
        const float e = expf(-a3);
        float tot = e;
#pragma unroll
        for (int off = 32; off > 0; off >>= 1) tot += __shfl_xor(tot, off);
        const float outv = e / tot;
        const float d3 = (tcur[tid] - outv) * a3 * (1.f - a3);
        sm[D3V_OFF + tid] = d3;
        sm[B3V_OFF + tid] -= LRC * d3;
      } else if (tid < 128) {
        const int lane = tid - 64, ln = (l + 1 < 32) ? l + 1 : 31;
#pragma unroll
        for (int u = 0; u < 4; u++)
          sm[Z1PRE_OFF + nxt * 256 + lane + u * 64] =
              z1pg[ln * 256 + lane + u * 64];
      } else if (tid < 192) {
        const int lane = tid - 128, ln = (l + 1 < 32) ? l + 1 : 31;
        if (lane < 32)
          sm[GPRE_OFF + nxt * 32 + lane] = G[(bs + ln) * 1024 + bs + lane];
      } else if (tid < 256) {
        const int lane = tid - 192, ln = (l + 1 < 32) ? l + 1 : 31;
        sm[TPRE_OFF + nxt * 64 + lane] = Tg[(bs + ln) * 64 + lane];
      }
      __syncthreads();
      // E: o2 rows (16 W3 rows) via q-shuffle-reduce
      {
        const float d0 = sm[D3V_OFF + q * 2], d1 = sm[D3V_OFF + q * 2 + 1];
#define EROW(j)                                                               \
        { float e = W3x_##j * d0 + W3y_##j * d1;                              \
          e = qreduce(e);                                                     \
          if (q == 0) {                                                       \
            const int r = p * 16 + j;                                         \
            const float a2x = sm[A2V_OFF + r];                                \
            const float o2 = e * a2x * (1.f - a2x);                           \
            sm[O2V_OFF + r] = o2;                                             \
            sm[B2V_OFF + r] -= LRC * o2; } }
        ROWS16(EROW)
      }
      __syncthreads();
      // F: o1 rows (9 reg + 7 LDS) via q-shuffle-reduce
      {
        const f32x8 ov8 = *(const f32x8*)(sm + O2V_OFF + q * 8);
#define FROWR(i)                                                              \
        { const f32x8 tmp = W2_##i * ov8; float e = hsum8(tmp);               \
          e = qreduce(e);                                                     \
          if (q == 0) {                                                       \
            const int r = p * 9 + i;                                          \
            const float a1x = sm[A1V_OFF + r];                                \
            const float o1x = e * a1x * (1.f - a1x);                          \
            sm[O1V_OFF + r] = o1x;                                            \
            sm[B1V_OFF + r] -= LRC * o1x; } }
        ROWS9(FROWR)
#define FROWL(i)                                                              \
        { const int gr = p * 7 + i;                                           \
          const float4 A4 = *(const float4*)(sm + W2LA_OFF + gr * 128 + q * 4); \
          const float4 B4 = *(const float4*)(sm + W2LB_OFF + gr * 128 + q * 4); \
          float e = A4.x * ov8.s0 + A4.y * ov8.s1 + A4.z * ov8.s2 +           \
                    A4.w * ov8.s3 + B4.x * ov8.s4 + B4.y * ov8.s5 +           \
                    B4.z * ov8.s6 + B4.w * ov8.s7;                            \
          e = qreduce(e);                                                     \
          if (q == 0) {                                                       \
            const int r = 144 + gr;                                           \
            const float a1x = sm[A1V_OFF + r];                                \
            const float o1x = e * a1x * (1.f - a1x);                          \
            sm[O1V_OFF + r] = o1x;                                            \
            sm[B1V_OFF + r] -= LRC * o1x; } }
        ROWS7(FROWL)
      }
      __syncthreads();
      // G: 11 dots over waves 0-7 (two rounds) + o1 copy-out (wave 3 r2)
      {
        const int lane = tid & 63;
        {
          float v = 0.f;
          if (w == 0)      { for (int i = lane; i < 256; i += 64) v += sm[Z1V_OFF+i] * sm[O1V_OFF+i]; }
          else if (w == 1) { for (int i = lane; i < 256; i += 64) v += sm[O1V_OFF+i] * sm[O1V_OFF+i]; }
          else if (w == 2) { for (int i = lane; i < 256; i += 64) v += sm[Z2V_OFF+i] * sm[O2V_OFF+i]; }
          else if (w == 3) { for (int i = lane; i < 256; i += 64) v += sm[A1V_OFF+i] * sm[A1V_OFF+i]; }
          else if (w == 4) { for (int i = lane; i < 256; i += 64) v += sm[O2V_OFF+i] * sm[O2V_OFF+i]; }
          else if (w == 5) { v = sm[Z3V_OFF+lane] * sm[D3V_OFF+lane]; }
          else if (w == 6) { for (int i = lane; i < 256; i += 64) v += sm[A2V_OFF+i] * sm[A2V_OFF+i]; }
          else             { v = sm[D3V_OFF+lane] * sm[D3V_OFF+lane]; }
#pragma unroll
          for (int off = 32; off > 0; off >>= 1) v += __shfl_xor(v, off);
          if (lane == 0) sm[DTS_OFF + w] = v;
        }
        if (w == 3) {
          ushort* o1h = (ushort*)(sm + O1H_OFF);
          for (int i = lane; i < 256; i += 64) {
            const float x = sm[O1V_OFF + i];
            o1g[t * 256 + i] = x;
            o1h[l * 264 + i] = f2bf(x);
          }
        } else if (w < 3) {
          float v = 0.f;
          if (w == 0)      { for (int i = lane; i < 256; i += 64) v += sm[B1V_OFF+i] * sm[B1V_OFF+i]; }
          else if (w == 1) { for (int i = lane; i < 256; i += 64) v += sm[B2V_OFF+i] * sm[B2V_OFF+i]; }
          else             { v = sm[B3V_OFF+lane] * sm[B3V_OFF+lane]; }
#pragma unroll
          for (int off = 32; off > 0; off >>= 1) v += __shfl_xor(v, off);
          if (lane == 0) sm[DTS_OFF + 8 + w] = v;
        }
      }
      __syncthreads();
      // H: replicated recurrences + rank-1 updates + renorm
      {
        const float c1 = -LRC / s1;
        const double gtt = (double)gcur[l];
        const double n1 = n1d + 2.0 * (double)c1 * (double)sm[DTS_OFF + 0] +
                          (double)c1 * (double)c1 * gtt * (double)sm[DTS_OFF + 1];
        n1d = n1;
        const double w1n = (double)s1 * sqrt(n1);
        s1 = (float)((double)s1 / fmax(w1n, (double)EPSV));
        if (tid == 0) { sm[CH_OFF + l] = c1; cg[t] = c1; }
        const float n2p = n2 - 2.f * LRC * sm[DTS_OFF + 2] +
                          LRC * LRC * sm[DTS_OFF + 3] * sm[DTS_OFF + 4];
        const float r2s = 1.f / fmaxf(sqrtf(n2p), EPSV);
        n2 = n2p * r2s * r2s;
        const float n3p = n3 - 2.f * LRC * sm[DTS_OFF + 5] +
                          LRC * LRC * sm[DTS_OFF + 6] * sm[DTS_OFF + 7];
        const float r3s = 1.f / fmaxf(sqrtf(n3p), EPSV);
        n3 = n3p * r3s * r3s;
        const float rb1 = 1.f / fmaxf(sqrtf(sm[DTS_OFF + 8]), EPSV);
        const float rb2 = 1.f / fmaxf(sqrtf(sm[DTS_OFF + 9]), EPSV);
        const float rb3 = 1.f / fmaxf(sqrtf(sm[DTS_OFF + 10]), EPSV);

        const f32x8 ovs = (-LRC * r2s) * (*(const f32x8*)(sm + O2V_OFF + q * 8));
#define HR(i)                                                                 \
        { const float a1x = sm[A1V_OFF + p * 9 + i];                          \
          W2_##i = W2_##i * r2s + a1x * ovs; }
        ROWS9(HR)
#define HL(i)                                                                 \
        { const int gr = p * 7 + i;                                           \
          const float a1x = sm[A1V_OFF + 144 + gr];                           \
          float4* pa4 = (float4*)(sm + W2LA_OFF + gr * 128 + q * 4);          \
          float4* pb4 = (float4*)(sm + W2LB_OFF + gr * 128 + q * 4);          \
          float4 A4 = *pa4; float4 B4 = *pb4;                                 \
          A4.x = A4.x * r2s + a1x * ovs.s0; A4.y = A4.y * r2s + a1x * ovs.s1; \
          A4.z = A4.z * r2s + a1x * ovs.s2; A4.w = A4.w * r2s + a1x * ovs.s3; \
          B4.x = B4.x * r2s + a1x * ovs.s4; B4.y = B4.y * r2s + a1x * ovs.s5; \
          B4.z = B4.z * r2s + a1x * ovs.s6; B4.w = B4.w * r2s + a1x * ovs.s7; \
          *pa4 = A4; *pb4 = B4; }
        ROWS7(HL)
        const float d0s = -LRC * r3s * sm[D3V_OFF + q * 2];
        const float d1s = -LRC * r3s * sm[D3V_OFF + q * 2 + 1];
#define HW3(j)                                                                \
        { const float a2x = sm[A2V_OFF + p * 16 + j];                         \
          W3x_##j = W3x_##j * r3s + a2x * d0s;                                \
          W3y_##j = W3y_##j * r3s + a2x * d1s; }
        ROWS16(HW3)
        if (tid < 256) {
          sm[B1V_OFF + tid] *= rb1;
          sm[B2V_OFF + tid] *= rb2;
        }
        if (tid < 64) sm[B3V_OFF + tid] *= rb3;
      }
      __syncthreads();
    }
  }

  if (tid == 0) sclg[0] = s1;
#define OW2(i) *(f32x8*)(outW2 + (p * 9 + i) * 256 + q * 8) = W2_##i;
  ROWS9(OW2)
#define OW2L(i)                                                               \
  { const int gr = p * 7 + i;                                                 \
    const float4 A4 = *(const float4*)(sm + W2LA_OFF + gr * 128 + q * 4);     \
    const float4 B4 = *(const float4*)(sm + W2LB_OFF + gr * 128 + q * 4);     \
    *(float4*)(outW2 + (144 + gr) * 256 + q * 8) = A4;                        \
    *(float4*)(outW2 + (144 + gr) * 256 + q * 8 + 4) = B4; }
  ROWS7(OW2L)
#define OW3(j)                                                                \
  { const int row = p * 16 + j;                                               \
    outW3[row * 64 + q * 2] = W3x_##j;                                        \
    outW3[row * 64 + q * 2 + 1] = W3y_##j; }
  ROWS16(OW3)
}

// ---------------------------------------------------------------- launch ----
extern "C" void kernel_launch(void* const* d_in, const int* in_sizes, int n_in,
                              void* d_out, int out_size, void* d_ws,
                              size_t ws_size, hipStream_t stream) {
  (void)in_sizes; (void)n_in; (void)out_size; (void)ws_size;
  const float* X   = (const float*)d_in[0];
  const float* Tg  = (const float*)d_in[1];
  const float* W1g = (const float*)d_in[2];
  const float* b1g = (const float*)d_in[3];
  const float* W2g = (const float*)d_in[4];
  const float* b2g = (const float*)d_in[5];
  const float* W3g = (const float*)d_in[6];
  const float* b3g = (const float*)d_in[7];
  float* out = (float*)d_out;
  float* ws  = (float*)d_ws;

  float* G    = ws;                  // 1048576
  float* Z10  = G + 1048576;         // 262144
  float* o1g  = Z10 + 262144;        // 262144
  float* cg   = o1g + 262144;        // 1024
  float* sclg = cg + 1024;           // 8
  float* z1pg = sclg + 8;            // 8192

  (void)hipFuncSetAttribute((const void*)k2_seq,
                            hipFuncAttributeMaxDynamicSharedMemorySize,
                            SMEM_BYTES);

  k_gram<<<dim3(16, 16), 256, 0, stream>>>(X, G);
  k_z10<<<dim3(4, 16), 256, 0, stream>>>(X, W1g, Z10);
  k2_seq<<<dim3(1), dim3(512), SMEM_BYTES, stream>>>(
      Tg, W1g, b1g, W2g, b2g, W3g, b3g, G, Z10, o1g, cg, z1pg, sclg,
      out + 262144, out + 327680);
  k_w1out<<<dim3(4, 16), 256, 0, stream>>>(X, o1g, cg, W1g, sclg, out);
}

// Round 11
// 33572.626 us; speedup vs baseline: 1.2195x; 1.1497x over previous
//
#include <hip/hip_runtime.h>
#include <math.h>

// Backprop_29188597744223 — 1024-step sequential MLP training scan.
//
//   k2_seq: ONE workgroup, 512 threads (8 waves = 2/SIMD; 1 wave/SIMD was a
//           3x disaster in R9). VGPR cap = 65536/threads = 128 (R2-R10).
//           W2 rows 0..143 in regs (9 f32x8/thread), rows 144..255 in LDS
//           split-plane q*4 b128 layout; W3 in regs. Phase exchanges use
//           R6's proven conflict-free layouts ([16][264], [*17+p], [256][9]
//           stride-9 with DPP quad-combines) — NO 5-level shuffle reduces
//           (R10's 37M-conflict swizzle storm). o1 history bf16 in LDS.
//           W1 lazy (Gram trick, ||U1||^2 in double, replicated).

#define LRC  0.01f
#define EPSV 1e-8f

typedef float f32x8 __attribute__((ext_vector_type(8)));
typedef unsigned int uint32;
typedef unsigned short ushort;

// ---- LDS layout (float offsets), total 40128 floats = 160512 B ----
#define W2LA_OFF  0        // [112][128]
#define W2LB_OFF  14336    // [112][128]
#define STG_OFF   28672    // 4224: prefix o1 fp32 [16][264] / o1h bf16 [32][264]ush
#define SCR_OFF   32896    // 4224: B1 [16][264] / C [128][17] / EF [256][9] / prefG [16][17]
#define Z1PRE_OFF 37120    // [2][256]
#define GPRE_OFF  37632    // [2][32]
#define TPRE_OFF  37696    // [2][64]
#define A1V_OFF   37824
#define Z1V_OFF   38080
#define Z2V_OFF   38336
#define A2V_OFF   38592
#define O2V_OFF   38848
#define O1V_OFF   39104
#define B1V_OFF   39360
#define B2V_OFF   39616
#define Z3V_OFF   39872    // 64
#define D3V_OFF   39936    // 64
#define B3V_OFF   40000    // 64
#define CH_OFF    40064    // 32
#define DTS_OFF   40096    // 16
#define CPRE_OFF  40112    // 16
#define SMEM_FLOATS 40128
#define SMEM_BYTES  (SMEM_FLOATS * 4)

#define ROWS9(OP)  OP(0) OP(1) OP(2) OP(3) OP(4) OP(5) OP(6) OP(7) OP(8)
#define ROWS7(OP)  OP(0) OP(1) OP(2) OP(3) OP(4) OP(5) OP(6)
#define ROWS16(OP)                                                            \
  OP(0) OP(1) OP(2) OP(3) OP(4) OP(5) OP(6) OP(7)                             \
  OP(8) OP(9) OP(10) OP(11) OP(12) OP(13) OP(14) OP(15)

__device__ __forceinline__ float hsum8(f32x8 v) {
  return ((v.s0 + v.s1) + (v.s2 + v.s3)) + ((v.s4 + v.s5) + (v.s6 + v.s7));
}
__device__ __forceinline__ ushort f2bf(float f) {
  uint32 u = __float_as_uint(f);
  return (ushort)((u + 0x7FFFu + ((u >> 16) & 1u)) >> 16);
}
__device__ __forceinline__ float bf2f(ushort h) {
  return __uint_as_float(((uint32)h) << 16);
}

#define FMA16(c, a, b)                                                        \
  c[0][0] += a.x * b.x; c[0][1] += a.x * b.y; c[0][2] += a.x * b.z; c[0][3] += a.x * b.w; \
  c[1][0] += a.y * b.x; c[1][1] += a.y * b.y; c[1][2] += a.y * b.z; c[1][3] += a.y * b.w; \
  c[2][0] += a.z * b.x; c[2][1] += a.z * b.y; c[2][2] += a.z * b.z; c[2][3] += a.z * b.w; \
  c[3][0] += a.w * b.x; c[3][1] += a.w * b.y; c[3][2] += a.w * b.z; c[3][3] += a.w * b.w;

// ---------------------------------------------------------------- k_gram ----
__global__ __launch_bounds__(256) void k_gram(const float* __restrict__ X,
                                              float* __restrict__ G) {
  const int bi = blockIdx.y, bj = blockIdx.x;
  if (bj > bi) return;
  __shared__ float Xa[32][68];
  __shared__ float Xb[32][68];
  const int tid = threadIdx.x;
  const int tx = tid & 15, ty = tid >> 4;
  float c[4][4] = {};
  for (int k0 = 0; k0 < 1024; k0 += 32) {
    __syncthreads();
    {
      const int row = tid >> 2, kk = (tid & 3) * 8;
      const float* pa = X + (bi * 64 + row) * 1024 + k0 + kk;
      const float4 a0 = *(const float4*)pa;
      const float4 a1 = *(const float4*)(pa + 4);
      Xa[kk + 0][row] = a0.x; Xa[kk + 1][row] = a0.y;
      Xa[kk + 2][row] = a0.z; Xa[kk + 3][row] = a0.w;
      Xa[kk + 4][row] = a1.x; Xa[kk + 5][row] = a1.y;
      Xa[kk + 6][row] = a1.z; Xa[kk + 7][row] = a1.w;
      const float* pb = X + (bj * 64 + row) * 1024 + k0 + kk;
      const float4 b0 = *(const float4*)pb;
      const float4 b1 = *(const float4*)(pb + 4);
      Xb[kk + 0][row] = b0.x; Xb[kk + 1][row] = b0.y;
      Xb[kk + 2][row] = b0.z; Xb[kk + 3][row] = b0.w;
      Xb[kk + 4][row] = b1.x; Xb[kk + 5][row] = b1.y;
      Xb[kk + 6][row] = b1.z; Xb[kk + 7][row] = b1.w;
    }
    __syncthreads();
#pragma unroll
    for (int kk = 0; kk < 32; kk++) {
      const float4 a = *(const float4*)&Xa[kk][ty * 4];
      const float4 b = *(const float4*)&Xb[kk][tx * 4];
      FMA16(c, a, b)
    }
  }
#pragma unroll
  for (int ii = 0; ii < 4; ii++) {
    *(float4*)(G + (bi * 64 + ty * 4 + ii) * 1024 + bj * 64 + tx * 4) =
        make_float4(c[ii][0], c[ii][1], c[ii][2], c[ii][3]);
  }
}

// ----------------------------------------------------------------- k_z10 ----
__global__ __launch_bounds__(256) void k_z10(const float* __restrict__ X,
                                             const float* __restrict__ W1g,
                                             float* __restrict__ Z10) {
  const int bi = blockIdx.y, bj = blockIdx.x;
  __shared__ float At[32][68];
  __shared__ float Bt[32][68];
  const int tid = threadIdx.x;
  const int tx = tid & 15, ty = tid >> 4;
  float c[4][4] = {};
  for (int k0 = 0; k0 < 1024; k0 += 32) {
    __syncthreads();
    {
      const int row = tid >> 2, kk = (tid & 3) * 8;
      const float* pa = X + (bi * 64 + row) * 1024 + k0 + kk;
      const float4 a0 = *(const float4*)pa;
      const float4 a1 = *(const float4*)(pa + 4);
      At[kk + 0][row] = a0.x; At[kk + 1][row] = a0.y;
      At[kk + 2][row] = a0.z; At[kk + 3][row] = a0.w;
      At[kk + 4][row] = a1.x; At[kk + 5][row] = a1.y;
      At[kk + 6][row] = a1.z; At[kk + 7][row] = a1.w;
      const int kr = tid >> 3, j8 = (tid & 7) * 8;
      const float* pb = W1g + (k0 + kr) * 256 + bj * 64 + j8;
      *(float4*)&Bt[kr][j8]     = *(const float4*)pb;
      *(float4*)&Bt[kr][j8 + 4] = *(const float4*)(pb + 4);
    }
    __syncthreads();
#pragma unroll
    for (int kk = 0; kk < 32; kk++) {
      const float4 a = *(const float4*)&At[kk][ty * 4];
      const float4 b = *(const float4*)&Bt[kk][tx * 4];
      FMA16(c, a, b)
    }
  }
#pragma unroll
  for (int ii = 0; ii < 4; ii++) {
    *(float4*)(Z10 + (bi * 64 + ty * 4 + ii) * 256 + bj * 64 + tx * 4) =
        make_float4(c[ii][0], c[ii][1], c[ii][2], c[ii][3]);
  }
}

// --------------------------------------------------------------- k_w1out ----
__global__ __launch_bounds__(256) void k_w1out(
    const float* __restrict__ X, const float* __restrict__ o1g,
    const float* __restrict__ cg, const float* __restrict__ W1g,
    const float* __restrict__ sclg, float* __restrict__ outW1) {
  const int bi = blockIdx.y, bj = blockIdx.x;
  __shared__ float At[32][68];
  __shared__ float Bt[32][68];
  const int tid = threadIdx.x;
  const int tx = tid & 15, ty = tid >> 4;
  float c[4][4] = {};
  for (int k0 = 0; k0 < 1024; k0 += 32) {
    __syncthreads();
    {
      const int kr = tid >> 3, m8 = (tid & 7) * 8;
      const float* pa = X + (k0 + kr) * 1024 + bi * 64 + m8;
      *(float4*)&At[kr][m8]     = *(const float4*)pa;
      *(float4*)&At[kr][m8 + 4] = *(const float4*)(pa + 4);
      const float cs = cg[k0 + kr];
      const float* pb = o1g + (k0 + kr) * 256 + bj * 64 + m8;
      float4 b0 = *(const float4*)pb;
      float4 b1 = *(const float4*)(pb + 4);
      b0.x *= cs; b0.y *= cs; b0.z *= cs; b0.w *= cs;
      b1.x *= cs; b1.y *= cs; b1.z *= cs; b1.w *= cs;
      *(float4*)&Bt[kr][m8]     = b0;
      *(float4*)&Bt[kr][m8 + 4] = b1;
    }
    __syncthreads();
#pragma unroll
    for (int kk = 0; kk < 32; kk++) {
      const float4 a = *(const float4*)&At[kk][ty * 4];
      const float4 b = *(const float4*)&Bt[kk][tx * 4];
      FMA16(c, a, b)
    }
  }
  const float s1f = sclg[0];
#pragma unroll
  for (int ii = 0; ii < 4; ii++) {
    const int row = bi * 64 + ty * 4 + ii;
    const float4 w = *(const float4*)(W1g + row * 256 + bj * 64 + tx * 4);
    *(float4*)(outW1 + row * 256 + bj * 64 + tx * 4) =
        make_float4(s1f * (w.x + c[ii][0]), s1f * (w.y + c[ii][1]),
                    s1f * (w.z + c[ii][2]), s1f * (w.w + c[ii][3]));
  }
}

// ---------------------------------------------------------------- k2_seq ----
__device__ __forceinline__ float block_reduce8(float v, float* tmp, int tid) {
#pragma unroll
  for (int off = 32; off > 0; off >>= 1) v += __shfl_xor(v, off);
  __syncthreads();
  if ((tid & 63) == 0) tmp[tid >> 6] = v;
  __syncthreads();
  float s = 0.f;
#pragma unroll
  for (int w = 0; w < 8; w++) s += tmp[w];
  __syncthreads();
  return s;
}

__global__ __launch_bounds__(512) void k2_seq(
    const float* __restrict__ Tg, const float* __restrict__ W1g,
    const float* __restrict__ b1g, const float* __restrict__ W2g,
    const float* __restrict__ b2g, const float* __restrict__ W3g,
    const float* __restrict__ b3g, const float* __restrict__ G,
    const float* __restrict__ Z10, float* __restrict__ o1g,
    float* __restrict__ cg, float* __restrict__ z1pg,
    float* __restrict__ sclg, float* __restrict__ outW2,
    float* __restrict__ outW3) {
  extern __shared__ float sm[];
  const int tid = threadIdx.x;
  const int p = tid >> 5;  // 0..15
  const int q = tid & 31;  // 0..31
  const int w = tid >> 6;  // wave 0..7

  // ---- persistent register state (named SSA; ~109 floats) ----
  f32x8 W2_0, W2_1, W2_2, W2_3, W2_4, W2_5, W2_6, W2_7, W2_8;
  float W3x_0, W3x_1, W3x_2, W3x_3, W3x_4, W3x_5, W3x_6, W3x_7,
        W3x_8, W3x_9, W3x_10, W3x_11, W3x_12, W3x_13, W3x_14, W3x_15;
  float W3y_0, W3y_1, W3y_2, W3y_3, W3y_4, W3y_5, W3y_6, W3y_7,
        W3y_8, W3y_9, W3y_10, W3y_11, W3y_12, W3y_13, W3y_14, W3y_15;

#define IW2(i) W2_##i = *(const f32x8*)(W2g + (p * 9 + i) * 256 + q * 8);
  ROWS9(IW2)
#define IW3(j)                                                                \
  { const int row = p * 16 + j;                                               \
    W3x_##j = W3g[row * 64 + q * 2];                                          \
    W3y_##j = W3g[row * 64 + q * 2 + 1]; }
  ROWS16(IW3)

  float acc2 = 0.f;
#define IW2L(i)                                                               \
  { const int gr = p * 7 + i;                                                 \
    const f32x8 tv = *(const f32x8*)(W2g + (144 + gr) * 256 + q * 8);         \
    *(float4*)(sm + W2LA_OFF + gr * 128 + q * 4) =                            \
        make_float4(tv.s0, tv.s1, tv.s2, tv.s3);                              \
    *(float4*)(sm + W2LB_OFF + gr * 128 + q * 4) =                            \
        make_float4(tv.s4, tv.s5, tv.s6, tv.s7);                              \
    const f32x8 t2 = tv * tv; acc2 += hsum8(t2); }
  ROWS7(IW2L)
#define N2R(i) { const f32x8 t2 = W2_##i * W2_##i; acc2 += hsum8(t2); }
  ROWS9(N2R)

  if (tid < 256) { sm[B1V_OFF + tid] = b1g[tid]; sm[B2V_OFF + tid] = b2g[tid]; }
  if (tid < 64) sm[B3V_OFF + tid] = b3g[tid];

  float acc1 = 0.f;
  for (int i = tid; i < 65536; i += 512) {
    const float4 v = ((const float4*)W1g)[i];
    acc1 += v.x * v.x + v.y * v.y + v.z * v.z + v.w * v.w;
  }
  __syncthreads();
  const float n1init = block_reduce8(acc1, sm + SCR_OFF, tid);
  const float n2init = block_reduce8(acc2, sm + SCR_OFF, tid);
  float acc3 = 0.f;
#define N3R(j) acc3 += W3x_##j * W3x_##j + W3y_##j * W3y_##j;
  ROWS16(N3R)
  const float n3init = block_reduce8(acc3, sm + SCR_OFF, tid);

  float s1 = 1.f;
  double n1d = (double)n1init;
  float n2 = n2init, n3 = n3init;
  __syncthreads();

  for (int b = 0; b < 32; b++) {
    const int bs = b * 32;
    // ---- prefix (2 passes x 16 rows): z1pg[r] = Z10[bs+r] + sum cg*G*o1
    for (int v = 0; v < 2; v++) {
      f32x8 pacc = {0.f, 0.f, 0.f, 0.f, 0.f, 0.f, 0.f, 0.f};
      const int rv = v * 16 + p;
      for (int c0 = 0; c0 < bs; c0 += 16) {
        __syncthreads();
#pragma unroll
        for (int u = 0; u < 2; u++) {
          const int fi = tid + u * 512;  // 1024 float4 = 16 x 256
          const int row = fi >> 6, c4 = fi & 63;
          *(float4*)(sm + STG_OFF + row * 264 + c4 * 4) =
              *(const float4*)(o1g + (c0 + row) * 256 + c4 * 4);
        }
        if (tid < 256) {
          const int rr = tid >> 4, s16 = tid & 15;
          sm[SCR_OFF + rr * 17 + s16] =
              G[(bs + v * 16 + rr) * 1024 + c0 + s16];
        }
        if (tid < 16) sm[CPRE_OFF + tid] = cg[c0 + tid];
        __syncthreads();
#pragma unroll
        for (int ss = 0; ss < 16; ss++) {
          const float g = sm[SCR_OFF + p * 17 + ss] * sm[CPRE_OFF + ss];
          pacc += g * (*(const f32x8*)(sm + STG_OFF + ss * 264 + q * 8));
        }
      }
      *(f32x8*)(z1pg + rv * 256 + q * 8) =
          *(const f32x8*)(Z10 + (bs + rv) * 256 + q * 8) + pacc;
    }
    __syncthreads();
    // prime prefetch slot 0
    if (tid < 256) sm[Z1PRE_OFF + tid] = z1pg[tid];
    else if (tid < 288) sm[GPRE_OFF + tid - 256] = G[bs * 1024 + bs + tid - 256];
    else if (tid < 352) sm[TPRE_OFF + tid - 288] = Tg[bs * 64 + tid - 288];
    __syncthreads();

    // ---- 32 sequential steps
    for (int l = 0; l < 32; l++) {
      const int t = bs + l;
      const int cur = l & 1, nxt = cur ^ 1;
      const float* z1cur = sm + Z1PRE_OFF + cur * 256;
      const float* gcur  = sm + GPRE_OFF + cur * 32;
      const float* tcur  = sm + TPRE_OFF + cur * 64;
      // A: z1u = z1p[l] + history (bf16, 2 thr/col); a1 = sigmoid
      {
        const int j = tid >> 1, half = tid & 1;
        const ushort* o1h = (const ushort*)(sm + STG_OFF);
        float a = 0.f;
        for (int lp = half; lp < l; lp += 2)
          a += sm[CH_OFF + lp] * gcur[lp] * bf2f(o1h[lp * 264 + j]);
        a += __shfl_xor(a, 1);
        if (half == 0) {
          const float z1u = z1cur[j] + a;
          sm[Z1V_OFF + j] = z1u;
          sm[A1V_OFF + j] =
              1.f / (1.f + expf(-(s1 * z1u + sm[B1V_OFF + j])));
        }
      }
      __syncthreads();
      // B1: z2 col-partials (9 reg + 7 LDS rows) -> [16][264] (R6 layout)
      {
        f32x8 acc = {0.f, 0.f, 0.f, 0.f, 0.f, 0.f, 0.f, 0.f};
#define B1R(i) acc += sm[A1V_OFF + p * 9 + i] * W2_##i;
        ROWS9(B1R)
#define B1L(i)                                                                \
        { const int gr = p * 7 + i;                                           \
          const float a1x = sm[A1V_OFF + 144 + gr];                           \
          const float4 A4 = *(const float4*)(sm + W2LA_OFF + gr * 128 + q * 4); \
          const float4 B4 = *(const float4*)(sm + W2LB_OFF + gr * 128 + q * 4); \
          acc.s0 += a1x * A4.x; acc.s1 += a1x * A4.y;                         \
          acc.s2 += a1x * A4.z; acc.s3 += a1x * A4.w;                         \
          acc.s4 += a1x * B4.x; acc.s5 += a1x * B4.y;                         \
          acc.s6 += a1x * B4.z; acc.s7 += a1x * B4.w; }
        ROWS7(B1L)
        *(f32x8*)(sm + SCR_OFF + p * 264 + q * 8) = acc;
      }
      __syncthreads();
      // B2
      if (tid < 256) {
        float s = 0.f;
#pragma unroll
        for (int pp = 0; pp < 16; pp++) s += sm[SCR_OFF + pp * 264 + tid];
        sm[Z2V_OFF + tid] = s;
        sm[A2V_OFF + tid] = 1.f / (1.f + expf(-(s + sm[B2V_OFF + tid])));
      }
      __syncthreads();
      // C1: z3 partials -> [(q*2+r)*17+p] (R6 layout, conflict-free)
      {
        float c0a = 0.f, c1a = 0.f;
#define C1R(j)                                                                \
        { const float a2x = sm[A2V_OFF + p * 16 + j];                         \
          c0a += a2x * W3x_##j; c1a += a2x * W3y_##j; }
        ROWS16(C1R)
        sm[SCR_OFF + (q * 2 + 0) * 17 + p] = c0a;
        sm[SCR_OFF + (q * 2 + 1) * 17 + p] = c1a;
      }
      __syncthreads();
      // C2 (wave 0) + prefetch next z1p/G-row/targets (waves 1-3)
      if (tid < 64) {
        float s = 0.f;
#pragma unroll
        for (int pp = 0; pp < 16; pp++) s += sm[SCR_OFF + tid * 17 + pp];
        sm[Z3V_OFF + tid] = s;
        const float a3 = 1.f / (1.f + expf(-(s + sm[B3V_OFF + tid])));
        const float e = expf(-a3);
        float tot = e;
#pragma unroll
        for (int off = 32; off > 0; off >>= 1) tot += __shfl_xor(tot, off);
        const float outv = e / tot;
        const float d3 = (tcur[tid] - outv) * a3 * (1.f - a3);
        sm[D3V_OFF + tid] = d3;
        sm[B3V_OFF + tid] -= LRC * d3;
      } else if (tid < 128) {
        const int lane = tid - 64, ln = (l + 1 < 32) ? l + 1 : 31;
#pragma unroll
        for (int u = 0; u < 4; u++)
          sm[Z1PRE_OFF + nxt * 256 + lane + u * 64] =
              z1pg[ln * 256 + lane + u * 64];
      } else if (tid < 192) {
        const int lane = tid - 128, ln = (l + 1 < 32) ? l + 1 : 31;
        if (lane < 32)
          sm[GPRE_OFF + nxt * 32 + lane] = G[(bs + ln) * 1024 + bs + lane];
      } else if (tid < 256) {
        const int lane = tid - 192, ln = (l + 1 < 32) ? l + 1 : 31;
        sm[TPRE_OFF + nxt * 64 + lane] = Tg[(bs + ln) * 64 + lane];
      }
      __syncthreads();
      // E1: o2 partials, DPP quad-combine -> [256][9] stride-9 (conflict-free)
      {
        const float d0 = sm[D3V_OFF + q * 2], d1 = sm[D3V_OFF + q * 2 + 1];
#define EROW(j)                                                               \
        { float e = W3x_##j * d0 + W3y_##j * d1;                              \
          e += __shfl_xor(e, 1); e += __shfl_xor(e, 2);                       \
          if ((q & 3) == 0)                                                   \
            sm[SCR_OFF + (p * 16 + j) * 9 + (q >> 2)] = e; }
        ROWS16(EROW)
      }
      __syncthreads();
      // E2
      if (tid < 256) {
        float s = 0.f;
#pragma unroll
        for (int g = 0; g < 8; g++) s += sm[SCR_OFF + tid * 9 + g];
        const float a2x = sm[A2V_OFF + tid];
        const float o2 = s * a2x * (1.f - a2x);
        sm[O2V_OFF + tid] = o2;
        sm[B2V_OFF + tid] -= LRC * o2;
      }
      __syncthreads();
      // F1: o1 row-dots (9 reg + 7 LDS), DPP quad-combine -> [256][9]
      {
        const f32x8 ov8 = *(const f32x8*)(sm + O2V_OFF + q * 8);
#define FROWR(i)                                                              \
        { const f32x8 tmp = W2_##i * ov8; float e = hsum8(tmp);               \
          e += __shfl_xor(e, 1); e += __shfl_xor(e, 2);                       \
          if ((q & 3) == 0)                                                   \
            sm[SCR_OFF + (p * 9 + i) * 9 + (q >> 2)] = e; }
        ROWS9(FROWR)
#define FROWL(i)                                                              \
        { const int gr = p * 7 + i;                                           \
          const float4 A4 = *(const float4*)(sm + W2LA_OFF + gr * 128 + q * 4); \
          const float4 B4 = *(const float4*)(sm + W2LB_OFF + gr * 128 + q * 4); \
          float e = A4.x * ov8.s0 + A4.y * ov8.s1 + A4.z * ov8.s2 +           \
                    A4.w * ov8.s3 + B4.x * ov8.s4 + B4.y * ov8.s5 +           \
                    B4.z * ov8.s6 + B4.w * ov8.s7;                            \
          e += __shfl_xor(e, 1); e += __shfl_xor(e, 2);                       \
          if ((q & 3) == 0)                                                   \
            sm[SCR_OFF + (144 + gr) * 9 + (q >> 2)] = e; }
        ROWS7(FROWL)
      }
      __syncthreads();
      // F2: o1, b1', o1 history (bf16) + o1g global
      if (tid < 256) {
        float s = 0.f;
#pragma unroll
        for (int g = 0; g < 8; g++) s += sm[SCR_OFF + tid * 9 + g];
        const float a1x = sm[A1V_OFF + tid];
        const float o1x = s * a1x * (1.f - a1x);
        sm[O1V_OFF + tid] = o1x;
        ((ushort*)(sm + STG_OFF))[l * 264 + tid] = f2bf(o1x);
        o1g[t * 256 + tid] = o1x;
        sm[B1V_OFF + tid] -= LRC * o1x;
      }
      __syncthreads();
      // G: 11 dots over 8 waves, two rounds
      {
        const int lane = tid & 63;
        {
          float v = 0.f;
          if (w == 0)      { for (int i = lane; i < 256; i += 64) v += sm[Z1V_OFF+i] * sm[O1V_OFF+i]; }
          else if (w == 1) { for (int i = lane; i < 256; i += 64) v += sm[O1V_OFF+i] * sm[O1V_OFF+i]; }
          else if (w == 2) { for (int i = lane; i < 256; i += 64) v += sm[Z2V_OFF+i] * sm[O2V_OFF+i]; }
          else if (w == 3) { for (int i = lane; i < 256; i += 64) v += sm[A1V_OFF+i] * sm[A1V_OFF+i]; }
          else if (w == 4) { for (int i = lane; i < 256; i += 64) v += sm[O2V_OFF+i] * sm[O2V_OFF+i]; }
          else if (w == 5) { v = sm[Z3V_OFF+lane] * sm[D3V_OFF+lane]; }
          else if (w == 6) { for (int i = lane; i < 256; i += 64) v += sm[A2V_OFF+i] * sm[A2V_OFF+i]; }
          else             { v = sm[D3V_OFF+lane] * sm[D3V_OFF+lane]; }
#pragma unroll
          for (int off = 32; off > 0; off >>= 1) v += __shfl_xor(v, off);
          if (lane == 0) sm[DTS_OFF + w] = v;
        }
        if (w < 3) {
          float v = 0.f;
          if (w == 0)      { for (int i = lane; i < 256; i += 64) v += sm[B1V_OFF+i] * sm[B1V_OFF+i]; }
          else if (w == 1) { for (int i = lane; i < 256; i += 64) v += sm[B2V_OFF+i] * sm[B2V_OFF+i]; }
          else             { v = sm[B3V_OFF+lane] * sm[B3V_OFF+lane]; }
#pragma unroll
          for (int off = 32; off > 0; off >>= 1) v += __shfl_xor(v, off);
          if (lane == 0) sm[DTS_OFF + 8 + w] = v;
        }
      }
      __syncthreads();
      // H: replicated recurrences + rank-1 updates + renorm
      {
        const float c1 = -LRC / s1;
        const double gtt = (double)gcur[l];
        const double n1 = n1d + 2.0 * (double)c1 * (double)sm[DTS_OFF + 0] +
                          (double)c1 * (double)c1 * gtt * (double)sm[DTS_OFF + 1];
        n1d = n1;
        const double w1n = (double)s1 * sqrt(n1);
        s1 = (float)((double)s1 / fmax(w1n, (double)EPSV));
        if (tid == 0) { sm[CH_OFF + l] = c1; cg[t] = c1; }
        const float n2p = n2 - 2.f * LRC * sm[DTS_OFF + 2] +
                          LRC * LRC * sm[DTS_OFF + 3] * sm[DTS_OFF + 4];
        const float r2s = 1.f / fmaxf(sqrtf(n2p), EPSV);
        n2 = n2p * r2s * r2s;
        const float n3p = n3 - 2.f * LRC * sm[DTS_OFF + 5] +
                          LRC * LRC * sm[DTS_OFF + 6] * sm[DTS_OFF + 7];
        const float r3s = 1.f / fmaxf(sqrtf(n3p), EPSV);
        n3 = n3p * r3s * r3s;
        const float rb1 = 1.f / fmaxf(sqrtf(sm[DTS_OFF + 8]), EPSV);
        const float rb2 = 1.f / fmaxf(sqrtf(sm[DTS_OFF + 9]), EPSV);
        const float rb3 = 1.f / fmaxf(sqrtf(sm[DTS_OFF + 10]), EPSV);

        const f32x8 ovs = (-LRC * r2s) * (*(const f32x8*)(sm + O2V_OFF + q * 8));
#define HR(i)                                                                 \
        { const float a1x = sm[A1V_OFF + p * 9 + i];                          \
          W2_##i = W2_##i * r2s + a1x * ovs; }
        ROWS9(HR)
#define HL(i)                                                                 \
        { const int gr = p * 7 + i;                                           \
          const float a1x = sm[A1V_OFF + 144 + gr];                           \
          float4* pa4 = (float4*)(sm + W2LA_OFF + gr * 128 + q * 4);          \
          float4* pb4 = (float4*)(sm + W2LB_OFF + gr * 128 + q * 4);          \
          float4 A4 = *pa4; float4 B4 = *pb4;                                 \
          A4.x = A4.x * r2s + a1x * ovs.s0; A4.y = A4.y * r2s + a1x * ovs.s1; \
          A4.z = A4.z * r2s + a1x * ovs.s2; A4.w = A4.w * r2s + a1x * ovs.s3; \
          B4.x = B4.x * r2s + a1x * ovs.s4; B4.y = B4.y * r2s + a1x * ovs.s5; \
          B4.z = B4.z * r2s + a1x * ovs.s6; B4.w = B4.w * r2s + a1x * ovs.s7; \
          *pa4 = A4; *pb4 = B4; }
        ROWS7(HL)
        const float d0s = -LRC * r3s * sm[D3V_OFF + q * 2];
        const float d1s = -LRC * r3s * sm[D3V_OFF + q * 2 + 1];
#define HW3(j)                                                                \
        { const float a2x = sm[A2V_OFF + p * 16 + j];                         \
          W3x_##j = W3x_##j * r3s + a2x * d0s;                                \
          W3y_##j = W3y_##j * r3s + a2x * d1s; }
        ROWS16(HW3)
        if (tid < 256) {
          sm[B1V_OFF + tid] *= rb1;
          sm[B2V_OFF + tid] *= rb2;
        }
        if (tid < 64) sm[B3V_OFF + tid] *= rb3;
      }
      __syncthreads();
    }
  }

  if (tid == 0) sclg[0] = s1;
#define OW2(i) *(f32x8*)(outW2 + (p * 9 + i) * 256 + q * 8) = W2_##i;
  ROWS9(OW2)
#define OW2L(i)                                                               \
  { const int gr = p * 7 + i;                                                 \
    const float4 A4 = *(const float4*)(sm + W2LA_OFF + gr * 128 + q * 4);     \
    const float4 B4 = *(const float4*)(sm + W2LB_OFF + gr * 128 + q * 4);     \
    *(float4*)(outW2 + (144 + gr) * 256 + q * 8) = A4;                        \
    *(float4*)(outW2 + (144 + gr) * 256 + q * 8 + 4) = B4; }
  ROWS7(OW2L)
#define OW3(j)                                                                \
  { const int row = p * 16 + j;                                               \
    outW3[row * 64 + q * 2] = W3x_##j;                                        \
    outW3[row * 64 + q * 2 + 1] = W3y_##j; }
  ROWS16(OW3)
}

// ---------------------------------------------------------------- launch ----
extern "C" void kernel_launch(void* const* d_in, const int* in_sizes, int n_in,
                              void* d_out, int out_size, void* d_ws,
                              size_t ws_size, hipStream_t stream) {
  (void)in_sizes; (void)n_in; (void)out_size; (void)ws_size;
  const float* X   = (const float*)d_in[0];
  const float* Tg  = (const float*)d_in[1];
  const float* W1g = (const float*)d_in[2];
  const float* b1g = (const float*)d_in[3];
  const float* W2g = (const float*)d_in[4];
  const float* b2g = (const float*)d_in[5];
  const float* W3g = (const float*)d_in[6];
  const float* b3g = (const float*)d_in[7];
  float* out = (float*)d_out;
  float* ws  = (float*)d_ws;

  float* G    = ws;                  // 1048576
  float* Z10  = G + 1048576;         // 262144
  float* o1g  = Z10 + 262144;        // 262144
  float* cg   = o1g + 262144;        // 1024
  float* sclg = cg + 1024;           // 8
  float* z1pg = sclg + 8;            // 8192

  (void)hipFuncSetAttribute((const void*)k2_seq,
                            hipFuncAttributeMaxDynamicSharedMemorySize,
                            SMEM_BYTES);

  k_gram<<<dim3(16, 16), 256, 0, stream>>>(X, G);
  k_z10<<<dim3(4, 16), 256, 0, stream>>>(X, W1g, Z10);
  k2_seq<<<dim3(1), dim3(512), SMEM_BYTES, stream>>>(
      Tg, W1g, b1g, W2g, b2g, W3g, b3g, G, Z10, o1g, cg, z1pg, sclg,
      out + 262144, out + 327680);
  k_w1out<<<dim3(4, 16), 256, 0, stream>>>(X, o1g, cg, W1g, sclg, out);
}